// Round 10
// baseline (281.128 us; speedup 1.0000x reference)
//
#include <hip/hip_runtime.h>
#include <hip/hip_bf16.h>
#include <math.h>

#define C_DIM 256
#define N_EMB 8192
#define N_Z   8192
#define HWB   1024
#define MBLK  64                  // z rows per filter block
#define NSPLIT 4                  // e splits; ns=bid&3 -> one split per XCD
#define SPLITC (N_EMB / NSPLIT)   // 2048 cols per split
#define NT    128                 // e cols per tile
#define NTILES (SPLITC / NT)      // 16
#define NCHUNK (NTILES * 4)       // 64 chunks (128 cols x 64 k, 16 KB each)
#define CK    48                  // candidate slots per row
#define EPS   1.1e-3f             // >= 2*hard bound |s_exact - s_approx| (~5e-4)
#define ZQ_ELEMS (N_Z * C_DIM)

typedef __attribute__((ext_vector_type(8))) short bf16x8;
typedef __attribute__((ext_vector_type(4))) float f32x4;
typedef unsigned short u16;
typedef unsigned int u32;

__device__ __forceinline__ float sqf(float x) { return __fmul_rn(x, x); }

__device__ __forceinline__ u16 f2bf(float v) {
  __hip_bfloat16 h = __float2bfloat16(v);
  u16 r; __builtin_memcpy(&r, &h, 2); return r;
}

// async global->LDS, 16B/lane; LDS dest = wave-uniform base + lane*16
__device__ __forceinline__ void g2l16(const u16* g, u16* l) {
  __builtin_amdgcn_global_load_lds(
      (const __attribute__((address_space(1))) unsigned int*)(const void*)g,
      (__attribute__((address_space(3))) unsigned int*)(void*)l, 16, 0, 0);
}

// Exact replication of numpy pairwise summation of 256 squared elements.
template <int STRIDE>
__device__ float pw_sumsq_256(const float* __restrict__ a) {
  float h[2];
#pragma unroll
  for (int hh = 0; hh < 2; ++hh) {
    const float* p = a + hh * 128 * STRIDE;
    float r0 = sqf(p[0 * STRIDE]), r1 = sqf(p[1 * STRIDE]);
    float r2 = sqf(p[2 * STRIDE]), r3 = sqf(p[3 * STRIDE]);
    float r4 = sqf(p[4 * STRIDE]), r5 = sqf(p[5 * STRIDE]);
    float r6 = sqf(p[6 * STRIDE]), r7 = sqf(p[7 * STRIDE]);
    for (int i = 8; i < 128; i += 8) {
      r0 = __fadd_rn(r0, sqf(p[(i + 0) * STRIDE]));
      r1 = __fadd_rn(r1, sqf(p[(i + 1) * STRIDE]));
      r2 = __fadd_rn(r2, sqf(p[(i + 2) * STRIDE]));
      r3 = __fadd_rn(r3, sqf(p[(i + 3) * STRIDE]));
      r4 = __fadd_rn(r4, sqf(p[(i + 4) * STRIDE]));
      r5 = __fadd_rn(r5, sqf(p[(i + 5) * STRIDE]));
      r6 = __fadd_rn(r6, sqf(p[(i + 6) * STRIDE]));
      r7 = __fadd_rn(r7, sqf(p[(i + 7) * STRIDE]));
    }
    h[hh] = __fadd_rn(__fadd_rn(__fadd_rn(r0, r1), __fadd_rn(r2, r3)),
                      __fadd_rn(__fadd_rn(r4, r5), __fadd_rn(r6, r7)));
  }
  return __fadd_rn(h[0], h[1]);
}

// exact sequential dot (k = 0..255 ascending, xyzw) -- identical op order to
// the verified exact path of rounds 1-9.
__device__ __forceinline__ float exact_score(const float* __restrict__ zr,
                                             const float* __restrict__ er,
                                             float z2v, float e2v) {
  float d = 0.f;
  for (int k4 = 0; k4 < 64; ++k4) {
    float4 a4 = *(const float4*)(zr + k4 * 4);
    float4 b4 = *(const float4*)(er + k4 * 4);
    d = fmaf(a4.x, b4.x, d); d = fmaf(a4.y, b4.y, d);
    d = fmaf(a4.z, b4.z, d); d = fmaf(a4.w, b4.w, d);
  }
  return __fsub_rn(__fadd_rn(z2v, e2v), __fmul_rn(2.f, d));
}

// Transpose hid [b][c][hw] -> zt fp32 [n][c] and zbf bf16 [n][c].
__global__ void vq_tr(const float* __restrict__ hid, float* __restrict__ zt,
                      u16* __restrict__ zbf) {
  __shared__ float tl[32][33];
  int t = threadIdx.x;
  int tx = t & 31, ty = t >> 5;
  int bb = blockIdx.x >> 8;
  int r = blockIdx.x & 255;
  int cT = r >> 5, hwT = r & 31;
#pragma unroll
  for (int p = 0; p < 4; ++p)
    tl[ty + p * 8][tx] =
        hid[((size_t)bb * C_DIM + cT * 32 + ty + p * 8) * HWB + hwT * 32 + tx];
  __syncthreads();
#pragma unroll
  for (int p = 0; p < 4; ++p) {
    float v = tl[tx][ty + p * 8];
    size_t oi = ((size_t)bb * HWB + hwT * 32 + ty + p * 8) * C_DIM + cT * 32 + tx;
    zt[oi] = v;
    zbf[oi] = f2bf(v);
  }
}

// blocks 0..31: e2 + ebf; blocks 32..63: z2 (from zt)
__global__ void vq_norms(const float* __restrict__ zt, const float* __restrict__ emb,
                         float* __restrict__ z2, float* __restrict__ e2,
                         u16* __restrict__ ebf) {
  int t = threadIdx.x, b = blockIdx.x;
  if (b < 32) {
    int r = b * 256 + t;
    e2[r] = pw_sumsq_256<1>(emb + (size_t)r * C_DIM);
    for (int k4 = 0; k4 < 64; ++k4) {
      float4 v = *(const float4*)(emb + (size_t)r * C_DIM + k4 * 4);
      ushort4 o;
      o.x = f2bf(v.x); o.y = f2bf(v.y); o.z = f2bf(v.z); o.w = f2bf(v.w);
      *(ushort4*)(ebf + (size_t)r * C_DIM + k4 * 4) = o;
    }
  } else {
    int n = (b - 32) * 256 + t;
    z2[n] = pw_sumsq_256<1>(zt + (size_t)n * C_DIM);
  }
}

// Single-pass MFMA filter + exact rescreen.
// Block: 256 thr = 4 waves (2x2) over 64 rows x 128 cols; wave tile 32x64.
// z (A) in registers (16 bf16x8/thread); e staged via global_load_lds into
// 2x16KB double buffer. Grid 512 = 2 blocks/CU (cross-block barrier overlap
// -- round 9's 1-block/CU config was latency-bound at every vmcnt(0) drain).
// Per-row running min in LDS (atomicMin on float bits); appends vs running
// threshold (superset of final-min+EPS set -> exact winner always captured;
// tile 0 re-barriers once for a tile-exact threshold). Candidates re-scored
// EXACTLY; rows overflowing CK (P~1e-10) -> exact full-split scan.
__global__ __launch_bounds__(256) void vq_filter(
    const u16* __restrict__ zbf, const u16* __restrict__ ebf,
    const float* __restrict__ zt, const float* __restrict__ emb,
    const float* __restrict__ z2g, const float* __restrict__ e2g,
    float* __restrict__ cd, int* __restrict__ ci) {
  __shared__ u16 el[2][8192];         // 32 KB: 2 bufs x (128 cols x 64 k)
  __shared__ float e2l[SPLITC];       // 8 KB
  __shared__ u32 mrow[MBLK];          // float bits of running row min
  __shared__ u16 rcol[MBLK * CK];     // 6 KB
  __shared__ int rcnt[MBLK];
  __shared__ int ovfr[MBLK];
  __shared__ int novf;
  __shared__ float wbs[4];
  __shared__ int wis[4];

  int t = threadIdx.x;
  int mb = blockIdx.x >> 2;           // 0..127
  int ns = blockIdx.x & 3;            // XCD x -> ns = x&3 (1 MB split, L2-local)
  int n0z = mb * MBLK;
  int l = t & 63;
  int w = t >> 6;
  int wr = w >> 1, wc = w & 1;        // 2x2 wave grid

  if (t < MBLK) { rcnt[t] = 0; mrow[t] = 0x7f800000u; }
  if (t == 0) novf = 0;
  for (int i = t; i < SPLITC; i += 256) e2l[i] = e2g[ns * SPLITC + i];

  // A fragments in registers: rows n0z + wr*32 + rf*16 + (l&15),
  // k = f*32 + (l>>4)*8  (same logical lane->k map as the B LDS reads).
  bf16x8 A[2][8];
#pragma unroll
  for (int rf = 0; rf < 2; ++rf)
#pragma unroll
    for (int f = 0; f < 8; ++f)
      A[rf][f] = *(const bf16x8*)(zbf +
          (size_t)(n0z + wr * 32 + rf * 16 + (l & 15)) * C_DIM + f * 32 + ((l >> 4) << 3));

  float z2r[2][4];
#pragma unroll
  for (int rf = 0; rf < 2; ++rf)
#pragma unroll
    for (int r = 0; r < 4; ++r)
      z2r[rf][r] = z2g[n0z + wr * 32 + rf * 16 + (l >> 4) * 4 + r];

  const f32x4 vzero = {0.f, 0.f, 0.f, 0.f};
  const u16* esplit = ebf + (size_t)(ns * SPLITC) * C_DIM;

  // stage one 16 KB chunk (tile tn_, k-offset kn_) into buffer nb_:
  // 4 g2l16 per thread; linear LDS dest, source pre-swizzled (slot^row&7).
#define STAGE_E(nb_, tn_, kn_)                                                \
  {                                                                           \
    const u16* bs_ = esplit + (size_t)((tn_) * NT) * C_DIM + (kn_);           \
    _Pragma("unroll")                                                         \
    for (int p_ = 0; p_ < 4; ++p_) {                                          \
      int o_ = (w * 4 + p_) * 64 + l;                                         \
      int rr_ = o_ >> 3, p3_ = o_ & 7;                                        \
      g2l16(bs_ + (size_t)rr_ * C_DIM + ((p3_ ^ (rr_ & 7)) << 3),             \
            &el[nb_][(w * 4 + p_) * 512]);                                    \
    }                                                                         \
  }

  STAGE_E(0, 0, 0)
  __syncthreads();   // drains chunk-0 DMA + LDS init

#pragma unroll 1
  for (int tile = 0; tile < NTILES; ++tile) {
    f32x4 acc[2][4];
#pragma unroll
    for (int rf = 0; rf < 2; ++rf)
#pragma unroll
      for (int cf = 0; cf < 4; ++cf) acc[rf][cf] = vzero;

#pragma unroll
    for (int kc = 0; kc < 4; ++kc) {     // chunk c = tile*4+kc; buf = kc&1
      {
        int c1 = tile * 4 + kc + 1;
        if (c1 < NCHUNK) STAGE_E((kc + 1) & 1, c1 >> 2, ((kc + 1) & 3) * 64)
      }
#pragma unroll
      for (int ks = 0; ks < 2; ++ks) {
        int phys = (((ks * 4 + (l >> 4)) ^ (l & 7)) << 3);
#pragma unroll
        for (int cf = 0; cf < 4; ++cf) {
          bf16x8 bfr = *(const bf16x8*)(&el[kc & 1][(wc * 64 + cf * 16 + (l & 15)) * 64 + phys]);
          acc[0][cf] = __builtin_amdgcn_mfma_f32_16x16x32_bf16(A[0][kc * 2 + ks], bfr, acc[0][cf], 0, 0, 0);
          acc[1][cf] = __builtin_amdgcn_mfma_f32_16x16x32_bf16(A[1][kc * 2 + ks], bfr, acc[1][cf], 0, 0, 0);
        }
      }
      if (kc == 3) {
        // epilogue: post lane-local row minima, then append vs running thr
        float e2s[4];
#pragma unroll
        for (int cf = 0; cf < 4; ++cf)
          e2s[cf] = e2l[tile * NT + wc * 64 + cf * 16 + (l & 15)];
#pragma unroll
        for (int rf = 0; rf < 2; ++rf)
#pragma unroll
          for (int r = 0; r < 4; ++r) {
            int rowl = wr * 32 + rf * 16 + (l >> 4) * 4 + r;
            float z2v = z2r[rf][r];
            float mn = INFINITY;
#pragma unroll
            for (int cf = 0; cf < 4; ++cf)
              mn = fminf(mn, fmaf(-2.f, acc[rf][cf][r], z2v + e2s[cf]));
            atomicMin(&mrow[rowl], __float_as_uint(mn));
          }
        if (tile == 0) __syncthreads();   // tile-exact threshold for tile 0
#pragma unroll
        for (int rf = 0; rf < 2; ++rf)
#pragma unroll
          for (int r = 0; r < 4; ++r) {
            int rowl = wr * 32 + rf * 16 + (l >> 4) * 4 + r;
            float z2v = z2r[rf][r];
            float thr = __uint_as_float(mrow[rowl]) + EPS;
#pragma unroll
            for (int cf = 0; cf < 4; ++cf) {
              float s = fmaf(-2.f, acc[rf][cf][r], z2v + e2s[cf]);
              if (s <= thr) {
                int pos = atomicAdd(&rcnt[rowl], 1);
                if (pos < CK)
                  rcol[rowl * CK + pos] = (u16)(ns * SPLITC + tile * NT + wc * 64 + cf * 16 + (l & 15));
              }
            }
          }
      }
      __syncthreads();   // drains next-chunk DMA + this buffer's reads
    }
  }

  // exact rescreen: 4 threads per row, strided over that row's candidates
  {
    int row = t >> 2;
    int cnt = rcnt[row];
    float b = INFINITY; int bi = N_EMB;
    if (cnt <= CK) {
      const float* zr = zt + (size_t)(n0z + row) * C_DIM;
      float z2v = z2g[n0z + row];
      for (int p2 = (t & 3); p2 < cnt; p2 += 4) {
        int col = rcol[row * CK + p2];
        float s = exact_score(zr, emb + (size_t)col * C_DIM, z2v, e2g[col]);
        if (s < b || (s == b && col < bi)) { b = s; bi = col; }
      }
    }
#pragma unroll
    for (int m = 1; m <= 2; m <<= 1) {
      float ob = __shfl_xor(b, m, 64);
      int oi2 = __shfl_xor(bi, m, 64);
      if (ob < b || (ob == b && oi2 < bi)) { b = ob; bi = oi2; }
    }
    if ((t & 3) == 0 && cnt <= CK) {
      cd[ns * N_Z + n0z + row] = b;
      ci[ns * N_Z + n0z + row] = bi;
    }
  }

  // overflow fallback: exact scan of the full split for any overflowed row
  if (t < MBLK && rcnt[t] > CK) {
    int p = atomicAdd(&novf, 1);
    ovfr[p] = t;
  }
  __syncthreads();
  int no = novf;
  for (int oi = 0; oi < no; ++oi) {
    int row = ovfr[oi];
    const float* zr = zt + (size_t)(n0z + row) * C_DIM;
    float z2v = z2g[n0z + row];
    float b = INFINITY; int bi = N_EMB;
#pragma unroll
    for (int q = 0; q < 8; ++q) {
      int col = ns * SPLITC + t * 8 + q;
      float s = exact_score(zr, emb + (size_t)col * C_DIM, z2v, e2g[col]);
      if (s < b || (s == b && col < bi)) { b = s; bi = col; }
    }
#pragma unroll
    for (int m = 1; m <= 32; m <<= 1) {
      float ob = __shfl_xor(b, m, 64);
      int oi2 = __shfl_xor(bi, m, 64);
      if (ob < b || (ob == b && oi2 < bi)) { b = ob; bi = oi2; }
    }
    if (l == 0) { wbs[w] = b; wis[w] = bi; }
    __syncthreads();
    if (t == 0) {
      for (int w2 = 1; w2 < 4; ++w2)
        if (wbs[w2] < b || (wbs[w2] == b && wis[w2] < bi)) { b = wbs[w2]; bi = wis[w2]; }
      cd[ns * N_Z + n0z + row] = b;
      ci[ns * N_Z + n0z + row] = bi;
    }
    __syncthreads();
  }
}

// merge NSPLIT candidates per row, write indices (as float) and gather z_q
__global__ void vq_out(const float* __restrict__ emb, const float* __restrict__ cd,
                       const int* __restrict__ ci, float* __restrict__ out) {
  __shared__ int sidx[32];
  int t = threadIdx.x;
  int n0 = blockIdx.x * 32;
  if (t < 32) {
    int n = n0 + t;
    float b = INFINITY;
    int bi = 0;
    for (int ns = 0; ns < NSPLIT; ++ns) {        // ascending split = ascending idx
      float d = cd[ns * N_Z + n];
      int i = ci[ns * N_Z + n];
      if (d < b || (d == b && i < bi)) { b = d; bi = i; }
    }
    sidx[t] = bi;
    out[ZQ_ELEMS + n] = (float)bi;
  }
  __syncthreads();
  int bb = n0 >> 10, hw0 = n0 & 1023;
  int nl = t & 31, cg = t >> 5;
#pragma unroll
  for (int p = 0; p < 8; ++p) {
    int c0 = cg * 4 + p * 32;
    float4 v = *(const float4*)(emb + (size_t)sidx[nl] * C_DIM + c0);
    out[((size_t)bb * C_DIM + c0 + 0) * HWB + hw0 + nl] = v.x;
    out[((size_t)bb * C_DIM + c0 + 1) * HWB + hw0 + nl] = v.y;
    out[((size_t)bb * C_DIM + c0 + 2) * HWB + hw0 + nl] = v.z;
    out[((size_t)bb * C_DIM + c0 + 3) * HWB + hw0 + nl] = v.w;
  }
}

extern "C" void kernel_launch(void* const* d_in, const int* in_sizes, int n_in,
                              void* d_out, int out_size, void* d_ws, size_t ws_size,
                              hipStream_t stream) {
  const float* hid = (const float*)d_in[0];
  const float* emb = (const float*)d_in[1];
  float* out = (float*)d_out;

  float* zt = (float*)d_ws;                        // 8 MB
  float* z2 = zt + (size_t)N_Z * C_DIM;            // 8192
  float* e2 = z2 + N_Z;                            // 8192
  float* cd = e2 + N_EMB;                          // NSPLIT*8192
  int* ci = (int*)(cd + (size_t)NSPLIT * N_Z);     // NSPLIT*8192
  u16* zbf = (u16*)(ci + (size_t)NSPLIT * N_Z);    // 4 MB
  u16* ebf = zbf + (size_t)N_Z * C_DIM;            // 4 MB

  vq_tr<<<2048, 256, 0, stream>>>(hid, zt, zbf);
  vq_norms<<<64, 256, 0, stream>>>(zt, emb, z2, e2, ebf);
  vq_filter<<<(N_Z / MBLK) * NSPLIT, 256, 0, stream>>>(zbf, ebf, zt, emb, z2, e2, cd, ci);
  vq_out<<<N_Z / 32, 256, 0, stream>>>(emb, cd, ci, out);
}

// Round 11
// 276.780 us; speedup vs baseline: 1.0157x; 1.0157x over previous
//
#include <hip/hip_runtime.h>
#include <hip/hip_bf16.h>
#include <math.h>

#define C_DIM 256
#define N_EMB 8192
#define N_Z   8192
#define HWB   1024
#define MBLK  64                  // z rows per filter block
#define NSPLIT 8                  // e splits; ns=bid&7 -> one split per XCD
#define SPLITC (N_EMB / NSPLIT)   // 1024 cols per split
#define NT    128                 // e cols per tile
#define NTILES (SPLITC / NT)      // 8
#define NCHUNK (NTILES * 4)       // 32 chunks (128 cols x 64 k, 16 KB each)
#define CK    48                  // candidate slots per row
#define EPS   1.1e-3f             // >= 2*hard bound |s_exact - s_approx| (~5e-4)
#define ZQ_ELEMS (N_Z * C_DIM)

typedef __attribute__((ext_vector_type(8))) short bf16x8;
typedef __attribute__((ext_vector_type(4))) float f32x4;
typedef unsigned short u16;
typedef unsigned int u32;

__device__ __forceinline__ float sqf(float x) { return __fmul_rn(x, x); }

__device__ __forceinline__ u16 f2bf(float v) {
  __hip_bfloat16 h = __float2bfloat16(v);
  u16 r; __builtin_memcpy(&r, &h, 2); return r;
}

// async global->LDS, 16B/lane; LDS dest = wave-uniform base + lane*16
__device__ __forceinline__ void g2l16(const u16* g, u16* l) {
  __builtin_amdgcn_global_load_lds(
      (const __attribute__((address_space(1))) unsigned int*)(const void*)g,
      (__attribute__((address_space(3))) unsigned int*)(void*)l, 16, 0, 0);
}

// Exact replication of numpy pairwise summation of 256 squared elements.
template <int STRIDE>
__device__ float pw_sumsq_256(const float* __restrict__ a) {
  float h[2];
#pragma unroll
  for (int hh = 0; hh < 2; ++hh) {
    const float* p = a + hh * 128 * STRIDE;
    float r0 = sqf(p[0 * STRIDE]), r1 = sqf(p[1 * STRIDE]);
    float r2 = sqf(p[2 * STRIDE]), r3 = sqf(p[3 * STRIDE]);
    float r4 = sqf(p[4 * STRIDE]), r5 = sqf(p[5 * STRIDE]);
    float r6 = sqf(p[6 * STRIDE]), r7 = sqf(p[7 * STRIDE]);
    for (int i = 8; i < 128; i += 8) {
      r0 = __fadd_rn(r0, sqf(p[(i + 0) * STRIDE]));
      r1 = __fadd_rn(r1, sqf(p[(i + 1) * STRIDE]));
      r2 = __fadd_rn(r2, sqf(p[(i + 2) * STRIDE]));
      r3 = __fadd_rn(r3, sqf(p[(i + 3) * STRIDE]));
      r4 = __fadd_rn(r4, sqf(p[(i + 4) * STRIDE]));
      r5 = __fadd_rn(r5, sqf(p[(i + 5) * STRIDE]));
      r6 = __fadd_rn(r6, sqf(p[(i + 6) * STRIDE]));
      r7 = __fadd_rn(r7, sqf(p[(i + 7) * STRIDE]));
    }
    h[hh] = __fadd_rn(__fadd_rn(__fadd_rn(r0, r1), __fadd_rn(r2, r3)),
                      __fadd_rn(__fadd_rn(r4, r5), __fadd_rn(r6, r7)));
  }
  return __fadd_rn(h[0], h[1]);
}

// exact sequential dot (k = 0..255 ascending, xyzw) -- identical op order to
// the verified exact path of rounds 1-10.
__device__ __forceinline__ float exact_score(const float* __restrict__ zr,
                                             const float* __restrict__ er,
                                             float z2v, float e2v) {
  float d = 0.f;
  for (int k4 = 0; k4 < 64; ++k4) {
    float4 a4 = *(const float4*)(zr + k4 * 4);
    float4 b4 = *(const float4*)(er + k4 * 4);
    d = fmaf(a4.x, b4.x, d); d = fmaf(a4.y, b4.y, d);
    d = fmaf(a4.z, b4.z, d); d = fmaf(a4.w, b4.w, d);
  }
  return __fsub_rn(__fadd_rn(z2v, e2v), __fmul_rn(2.f, d));
}

// Transpose hid [b][c][hw] -> zt fp32 [n][c] and zbf bf16 [n][c].
__global__ void vq_tr(const float* __restrict__ hid, float* __restrict__ zt,
                      u16* __restrict__ zbf) {
  __shared__ float tl[32][33];
  int t = threadIdx.x;
  int tx = t & 31, ty = t >> 5;
  int bb = blockIdx.x >> 8;
  int r = blockIdx.x & 255;
  int cT = r >> 5, hwT = r & 31;
#pragma unroll
  for (int p = 0; p < 4; ++p)
    tl[ty + p * 8][tx] =
        hid[((size_t)bb * C_DIM + cT * 32 + ty + p * 8) * HWB + hwT * 32 + tx];
  __syncthreads();
#pragma unroll
  for (int p = 0; p < 4; ++p) {
    float v = tl[tx][ty + p * 8];
    size_t oi = ((size_t)bb * HWB + hwT * 32 + ty + p * 8) * C_DIM + cT * 32 + tx;
    zt[oi] = v;
    zbf[oi] = f2bf(v);
  }
}

// blocks 0..31: e2 + ebf; blocks 32..63: z2 (from zt)
__global__ void vq_norms(const float* __restrict__ zt, const float* __restrict__ emb,
                         float* __restrict__ z2, float* __restrict__ e2,
                         u16* __restrict__ ebf) {
  int t = threadIdx.x, b = blockIdx.x;
  if (b < 32) {
    int r = b * 256 + t;
    e2[r] = pw_sumsq_256<1>(emb + (size_t)r * C_DIM);
    for (int k4 = 0; k4 < 64; ++k4) {
      float4 v = *(const float4*)(emb + (size_t)r * C_DIM + k4 * 4);
      ushort4 o;
      o.x = f2bf(v.x); o.y = f2bf(v.y); o.z = f2bf(v.z); o.w = f2bf(v.w);
      *(ushort4*)(ebf + (size_t)r * C_DIM + k4 * 4) = o;
    }
  } else {
    int n = (b - 32) * 256 + t;
    z2[n] = pw_sumsq_256<1>(zt + (size_t)n * C_DIM);
  }
}

// Single-pass MFMA filter + exact rescreen.
// Block: 256 thr = 4 waves (2x2) over 64 rows x 128 cols; wave tile 32x64.
// z (A) in registers; e staged via global_load_lds into 2x16KB double buffer.
// Grid 1024 (NSPLIT=8, ns=bid&7 -> one 0.5MB split per XCD), ~3 blocks/CU.
// Running per-row min in LDS mrow[], maintained by CONDITIONAL atomicMin:
// a lane posts only when its tile-min improves its register cache thrc[]
// (round 10's unconditional 16-way same-address atomics cost 7.9M conflict
// cycles). Appends use min(thrc, mrow)+EPS -- thresholds only shrink, so the
// set is a superset of the final-min+EPS set and the exact winner is always
// captured (tile 0 re-barriers once for a tile-exact initial threshold).
// Candidates re-scored EXACTLY; rows overflowing CK -> exact full-split scan.
__global__ __launch_bounds__(256) void vq_filter(
    const u16* __restrict__ zbf, const u16* __restrict__ ebf,
    const float* __restrict__ zt, const float* __restrict__ emb,
    const float* __restrict__ z2g, const float* __restrict__ e2g,
    float* __restrict__ cd, int* __restrict__ ci) {
  __shared__ u16 el[2][8192];         // 32 KB: 2 bufs x (128 cols x 64 k)
  __shared__ float e2l[SPLITC];       // 4 KB
  __shared__ u32 mrow[MBLK];          // float bits of running row min
  __shared__ u16 rcol[MBLK * CK];     // 6 KB
  __shared__ int rcnt[MBLK];
  __shared__ int ovfr[MBLK];
  __shared__ int novf;
  __shared__ float wbs[4];
  __shared__ int wis[4];

  int t = threadIdx.x;
  int mb = blockIdx.x >> 3;           // 0..127
  int ns = blockIdx.x & 7;            // XCD x -> ns = x (0.5 MB split, L2-local)
  int n0z = mb * MBLK;
  int l = t & 63;
  int w = t >> 6;
  int wr = w >> 1, wc = w & 1;        // 2x2 wave grid

  if (t < MBLK) { rcnt[t] = 0; mrow[t] = 0x7f800000u; }
  if (t == 0) novf = 0;
  for (int i = t; i < SPLITC; i += 256) e2l[i] = e2g[ns * SPLITC + i];

  // A fragments in registers: rows n0z + wr*32 + rf*16 + (l&15),
  // k = f*32 + (l>>4)*8  (same logical lane->k map as the B LDS reads).
  bf16x8 A[2][8];
#pragma unroll
  for (int rf = 0; rf < 2; ++rf)
#pragma unroll
    for (int f = 0; f < 8; ++f)
      A[rf][f] = *(const bf16x8*)(zbf +
          (size_t)(n0z + wr * 32 + rf * 16 + (l & 15)) * C_DIM + f * 32 + ((l >> 4) << 3));

  float z2r[2][4];
#pragma unroll
  for (int rf = 0; rf < 2; ++rf)
#pragma unroll
    for (int r = 0; r < 4; ++r)
      z2r[rf][r] = z2g[n0z + wr * 32 + rf * 16 + (l >> 4) * 4 + r];

  float thrc[2][4];                   // register cache of row min (no EPS)
#pragma unroll
  for (int rf = 0; rf < 2; ++rf)
#pragma unroll
    for (int r = 0; r < 4; ++r) thrc[rf][r] = INFINITY;

  const f32x4 vzero = {0.f, 0.f, 0.f, 0.f};
  const u16* esplit = ebf + (size_t)(ns * SPLITC) * C_DIM;

  // stage one 16 KB chunk (tile tn_, k-offset kn_) into buffer nb_:
  // 4 g2l16 per thread; linear LDS dest, source pre-swizzled (slot^row&7).
#define STAGE_E(nb_, tn_, kn_)                                                \
  {                                                                           \
    const u16* bs_ = esplit + (size_t)((tn_) * NT) * C_DIM + (kn_);           \
    _Pragma("unroll")                                                         \
    for (int p_ = 0; p_ < 4; ++p_) {                                          \
      int o_ = (w * 4 + p_) * 64 + l;                                         \
      int rr_ = o_ >> 3, p3_ = o_ & 7;                                        \
      g2l16(bs_ + (size_t)rr_ * C_DIM + ((p3_ ^ (rr_ & 7)) << 3),             \
            &el[nb_][(w * 4 + p_) * 512]);                                    \
    }                                                                         \
  }

  STAGE_E(0, 0, 0)
  __syncthreads();   // drains chunk-0 DMA + LDS init

#pragma unroll 1
  for (int tile = 0; tile < NTILES; ++tile) {
    f32x4 acc[2][4];
#pragma unroll
    for (int rf = 0; rf < 2; ++rf)
#pragma unroll
      for (int cf = 0; cf < 4; ++cf) acc[rf][cf] = vzero;

#pragma unroll
    for (int kc = 0; kc < 4; ++kc) {     // chunk c = tile*4+kc; buf = kc&1
      {
        int c1 = tile * 4 + kc + 1;
        if (c1 < NCHUNK) STAGE_E((kc + 1) & 1, c1 >> 2, ((kc + 1) & 3) * 64)
      }
#pragma unroll
      for (int ks = 0; ks < 2; ++ks) {
        int phys = (((ks * 4 + (l >> 4)) ^ (l & 7)) << 3);
#pragma unroll
        for (int cf = 0; cf < 4; ++cf) {
          bf16x8 bfr = *(const bf16x8*)(&el[kc & 1][(wc * 64 + cf * 16 + (l & 15)) * 64 + phys]);
          acc[0][cf] = __builtin_amdgcn_mfma_f32_16x16x32_bf16(A[0][kc * 2 + ks], bfr, acc[0][cf], 0, 0, 0);
          acc[1][cf] = __builtin_amdgcn_mfma_f32_16x16x32_bf16(A[1][kc * 2 + ks], bfr, acc[1][cf], 0, 0, 0);
        }
      }
      if (kc == 3) {
        float e2s[4];
#pragma unroll
        for (int cf = 0; cf < 4; ++cf)
          e2s[cf] = e2l[tile * NT + wc * 64 + cf * 16 + (l & 15)];
        // 1) post improved minima only (conditional atomic: rare after warmup)
#pragma unroll
        for (int rf = 0; rf < 2; ++rf)
#pragma unroll
          for (int r = 0; r < 4; ++r) {
            int rowl = wr * 32 + rf * 16 + (l >> 4) * 4 + r;
            float z2v = z2r[rf][r];
            float mn = INFINITY;
#pragma unroll
            for (int cf = 0; cf < 4; ++cf)
              mn = fminf(mn, fmaf(-2.f, acc[rf][cf][r], z2v + e2s[cf]));
            if (mn < thrc[rf][r]) {
              atomicMin(&mrow[rowl], __float_as_uint(mn));
              thrc[rf][r] = mn;
            }
          }
        if (tile == 0) __syncthreads();   // tile-exact threshold for tile 0
        // 2) appends vs refreshed threshold (mrow read = broadcast, free)
#pragma unroll
        for (int rf = 0; rf < 2; ++rf)
#pragma unroll
          for (int r = 0; r < 4; ++r) {
            int rowl = wr * 32 + rf * 16 + (l >> 4) * 4 + r;
            float cur = __uint_as_float(mrow[rowl]);
            thrc[rf][r] = fminf(thrc[rf][r], cur);
            float thr = thrc[rf][r] + EPS;
            float z2v = z2r[rf][r];
#pragma unroll
            for (int cf = 0; cf < 4; ++cf) {
              float s = fmaf(-2.f, acc[rf][cf][r], z2v + e2s[cf]);
              if (s <= thr) {
                int pos = atomicAdd(&rcnt[rowl], 1);
                if (pos < CK)
                  rcol[rowl * CK + pos] = (u16)(ns * SPLITC + tile * NT + wc * 64 + cf * 16 + (l & 15));
              }
            }
          }
      }
      __syncthreads();   // drains next-chunk DMA + this buffer's reads
    }
  }

  // exact rescreen: 4 threads per row, strided over that row's candidates
  {
    int row = t >> 2;
    int cnt = rcnt[row];
    float b = INFINITY; int bi = N_EMB;
    if (cnt <= CK) {
      const float* zr = zt + (size_t)(n0z + row) * C_DIM;
      float z2v = z2g[n0z + row];
      for (int p2 = (t & 3); p2 < cnt; p2 += 4) {
        int col = rcol[row * CK + p2];
        float s = exact_score(zr, emb + (size_t)col * C_DIM, z2v, e2g[col]);
        if (s < b || (s == b && col < bi)) { b = s; bi = col; }
      }
    }
#pragma unroll
    for (int m = 1; m <= 2; m <<= 1) {
      float ob = __shfl_xor(b, m, 64);
      int oi2 = __shfl_xor(bi, m, 64);
      if (ob < b || (ob == b && oi2 < bi)) { b = ob; bi = oi2; }
    }
    if ((t & 3) == 0 && cnt <= CK) {
      cd[ns * N_Z + n0z + row] = b;
      ci[ns * N_Z + n0z + row] = bi;
    }
  }

  // overflow fallback: exact scan of the full split for any overflowed row
  if (t < MBLK && rcnt[t] > CK) {
    int p = atomicAdd(&novf, 1);
    ovfr[p] = t;
  }
  __syncthreads();
  int no = novf;
  for (int oi = 0; oi < no; ++oi) {
    int row = ovfr[oi];
    const float* zr = zt + (size_t)(n0z + row) * C_DIM;
    float z2v = z2g[n0z + row];
    float b = INFINITY; int bi = N_EMB;
#pragma unroll
    for (int q = 0; q < 4; ++q) {
      int col = ns * SPLITC + t * 4 + q;
      float s = exact_score(zr, emb + (size_t)col * C_DIM, z2v, e2g[col]);
      if (s < b || (s == b && col < bi)) { b = s; bi = col; }
    }
#pragma unroll
    for (int m = 1; m <= 32; m <<= 1) {
      float ob = __shfl_xor(b, m, 64);
      int oi2 = __shfl_xor(bi, m, 64);
      if (ob < b || (ob == b && oi2 < bi)) { b = ob; bi = oi2; }
    }
    if (l == 0) { wbs[w] = b; wis[w] = bi; }
    __syncthreads();
    if (t == 0) {
      for (int w2 = 1; w2 < 4; ++w2)
        if (wbs[w2] < b || (wbs[w2] == b && wis[w2] < bi)) { b = wbs[w2]; bi = wis[w2]; }
      cd[ns * N_Z + n0z + row] = b;
      ci[ns * N_Z + n0z + row] = bi;
    }
    __syncthreads();
  }
}

// merge NSPLIT candidates per row, write indices (as float) and gather z_q
__global__ void vq_out(const float* __restrict__ emb, const float* __restrict__ cd,
                       const int* __restrict__ ci, float* __restrict__ out) {
  __shared__ int sidx[32];
  int t = threadIdx.x;
  int n0 = blockIdx.x * 32;
  if (t < 32) {
    int n = n0 + t;
    float b = INFINITY;
    int bi = 0;
    for (int ns = 0; ns < NSPLIT; ++ns) {        // ascending split = ascending idx
      float d = cd[ns * N_Z + n];
      int i = ci[ns * N_Z + n];
      if (d < b || (d == b && i < bi)) { b = d; bi = i; }
    }
    sidx[t] = bi;
    out[ZQ_ELEMS + n] = (float)bi;
  }
  __syncthreads();
  int bb = n0 >> 10, hw0 = n0 & 1023;
  int nl = t & 31, cg = t >> 5;
#pragma unroll
  for (int p = 0; p < 8; ++p) {
    int c0 = cg * 4 + p * 32;
    float4 v = *(const float4*)(emb + (size_t)sidx[nl] * C_DIM + c0);
    out[((size_t)bb * C_DIM + c0 + 0) * HWB + hw0 + nl] = v.x;
    out[((size_t)bb * C_DIM + c0 + 1) * HWB + hw0 + nl] = v.y;
    out[((size_t)bb * C_DIM + c0 + 2) * HWB + hw0 + nl] = v.z;
    out[((size_t)bb * C_DIM + c0 + 3) * HWB + hw0 + nl] = v.w;
  }
}

extern "C" void kernel_launch(void* const* d_in, const int* in_sizes, int n_in,
                              void* d_out, int out_size, void* d_ws, size_t ws_size,
                              hipStream_t stream) {
  const float* hid = (const float*)d_in[0];
  const float* emb = (const float*)d_in[1];
  float* out = (float*)d_out;

  float* zt = (float*)d_ws;                        // 8 MB
  float* z2 = zt + (size_t)N_Z * C_DIM;            // 8192
  float* e2 = z2 + N_Z;                            // 8192
  float* cd = e2 + N_EMB;                          // NSPLIT*8192
  int* ci = (int*)(cd + (size_t)NSPLIT * N_Z);     // NSPLIT*8192
  u16* zbf = (u16*)(ci + (size_t)NSPLIT * N_Z);    // 4 MB
  u16* ebf = zbf + (size_t)N_Z * C_DIM;            // 4 MB

  vq_tr<<<2048, 256, 0, stream>>>(hid, zt, zbf);
  vq_norms<<<64, 256, 0, stream>>>(zt, emb, z2, e2, ebf);
  vq_filter<<<(N_Z / MBLK) * NSPLIT, 256, 0, stream>>>(zbf, ebf, zt, emb, z2, e2, cd, ci);
  vq_out<<<N_Z / 32, 256, 0, stream>>>(emb, cd, ci, out);
}